// Round 3
// baseline (355.676 us; speedup 1.0000x reference)
//
#include <hip/hip_runtime.h>
#include <hip/hip_bf16.h>
#include <math.h>

// ---------------------------------------------------------------------------
// JointAttention fp16 MFMA pipeline.
//   convert fp32->fp16 -> pack W^T -> Q/K/V proj GEMMs (BK=64, glds,
//   head-blocked tile-contiguous outputs) -> V transpose -> flash attn
//   (S^T form, TK=128, exp2 no-max softmax, l via ones-MFMA, 2 barriers/iter)
//   -> output GEMM (128x64 tiles, fp32 out).
// Layouts:
//   qbuf [bh][2048][64]           (Q pre-scaled by 0.125*log2e)
//   kbuf [bh][kt32][ks2][tok128][32]    (16KB contiguous staging tiles)
//   vbuf [bh][4096][64]
//   vt   [bh][kt32][kks4][d64][32]      (16KB contiguous V^T staging tiles)
//   abuf [tok4096][1024]
// ---------------------------------------------------------------------------

typedef _Float16 f16;
typedef _Float16 f16x8 __attribute__((ext_vector_type(8)));
typedef _Float16 f16x4v __attribute__((ext_vector_type(4)));
typedef float    f32x4 __attribute__((ext_vector_type(4)));

#define MFMA_F16(a, b, c) __builtin_amdgcn_mfma_f32_16x16x32_f16((a), (b), (c), 0, 0, 0)

#define QSCALE 0.18033688011112042f   // 0.125 * log2(e)
#define EXPOFF 7.2134752044448170f    // 5 * log2(e)

__device__ __forceinline__ void glds16(const f16* g, f16* l) {
    __builtin_amdgcn_global_load_lds(
        (const __attribute__((address_space(1))) void*)g,
        (__attribute__((address_space(3))) void*)l, 16, 0, 0);
}

// ---------------------------------------------------------------------------
// fp32 -> fp16 convert of x and context
// ---------------------------------------------------------------------------
__global__ __launch_bounds__(256) void convert_xc(
    const float4* __restrict__ x, const float4* __restrict__ ctx,
    f16x4v* __restrict__ xb, f16x4v* __restrict__ cb)
{
    const int n4 = (2 * 2048 * 1024) / 4;
    int i = blockIdx.x * 256 + threadIdx.x;
    float4 v;
    f16x4v* dst;
    if (i < n4) { v = x[i];        dst = xb + i; }
    else        { v = ctx[i - n4]; dst = cb + (i - n4); }
    f16x4v h = { (f16)v.x, (f16)v.y, (f16)v.z, (f16)v.w };
    *dst = h;
}

// ---------------------------------------------------------------------------
// pack 6 weights W[K][N] fp32 -> Wt[N][K] fp16
// ---------------------------------------------------------------------------
__global__ __launch_bounds__(256) void pack_w(
    const float* __restrict__ W0, const float* __restrict__ W1,
    const float* __restrict__ W2, const float* __restrict__ W3,
    const float* __restrict__ W4, const float* __restrict__ W5,
    f16* __restrict__ out)
{
    const float* Ws[6] = { W0, W1, W2, W3, W4, W5 };
    const float* W = Ws[blockIdx.z];
    f16* Wt = out + (size_t)blockIdx.z * (1024 * 1024);

    __shared__ float tile[32][33];
    const int tx = threadIdx.x & 31, ty = threadIdx.x >> 5;
    const int n0 = blockIdx.x * 32, k0 = blockIdx.y * 32;

#pragma unroll
    for (int i = 0; i < 4; ++i) {
        int r = i * 8 + ty;
        tile[r][tx] = W[(size_t)(k0 + r) * 1024 + n0 + tx];
    }
    __syncthreads();
#pragma unroll
    for (int i = 0; i < 4; ++i) {
        int r = i * 8 + ty;
        Wt[(size_t)(n0 + r) * 1024 + k0 + tx] = (f16)tile[tx][r];
    }
}

// ---------------------------------------------------------------------------
// GEMM 128xBN tile, BK=64 (two k-steps per barrier pair), glds staging.
// LDS layout [ks][rows][32h]: flat chunk index == global chunk order.
// MODE: 0 = plain fp32 out [row][1024]
//       1 = Q: scale by QSCALE, head-blocked [bh][2048][64]
//       2 = K: tiled [bh][kt][ks][128][32]
//       3 = V: head-blocked [bh][4096][64]
// ---------------------------------------------------------------------------
template <int MODE, int BN, typename OutT>
__global__ __launch_bounds__(256) void gemm_kernel(
    const f16* __restrict__ A0, const f16* __restrict__ A1,
    const f16* __restrict__ Wt,
    const float* __restrict__ bias0, const float* __restrict__ bias1,
    OutT* __restrict__ out)
{
    __shared__ alignas(16) f16 As[2 * 128 * 32];      // 16 KB
    __shared__ alignas(16) f16 Bs[2 * BN * 32];       // 16/8 KB

    const int z = blockIdx.z;
    const f16* A = z ? A1 : A0;
    const f16* Bt = Wt + (size_t)z * 2097152;
    const float* bias = z ? bias1 : bias0;
    const int roff = z * 2048;

    const int m0 = blockIdx.x * 128, n0 = blockIdx.y * BN;
    const int tid = threadIdx.x;
    const int w = tid >> 6, lane = tid & 63, quad = lane >> 4, l15 = lane & 15;
    const int wm = (w >> 1) * 64, wn = (w & 1) * (BN / 2);
    constexpr int NF = BN / 32;            // b-frags per wave per k-step
    constexpr int APASS = 4;               // 1024 A chunks / 256 thr
    constexpr int BPASS = BN / 32;         // BN*4 chunks / 256 thr

    // per-lane global chunk offsets (identity LDS placement)
    int gA[APASS], gB[BPASS];
#pragma unroll
    for (int p = 0; p < APASS; ++p) {
        int c = tid + p * 256;
        gA[p] = (m0 + ((c >> 2) & 127)) * 1024 + (c >> 9) * 32 + (c & 3) * 8;
    }
#pragma unroll
    for (int p = 0; p < BPASS; ++p) {
        int c = tid + p * 256;
        gB[p] = (n0 + ((c >> 2) & (BN - 1))) * 1024 + (c / (BN * 4)) * 32 + (c & 3) * 8;
    }
    f16* asl = &As[w * 512];
    f16* bsl = &Bs[w * 512];

    f32x4 acc[4][NF] = {};

    for (int k0 = 0; k0 < 1024; k0 += 64) {
        __syncthreads();
#pragma unroll
        for (int p = 0; p < APASS; ++p)
            glds16(&A[gA[p] + k0], asl + p * 2048);
#pragma unroll
        for (int p = 0; p < BPASS; ++p)
            glds16(&Bt[gB[p] + k0], bsl + p * 2048);
        __syncthreads();

#pragma unroll
        for (int ks = 0; ks < 2; ++ks) {
            f16x8 a[4], b[NF];
#pragma unroll
            for (int i = 0; i < 4; ++i)
                a[i] = *(const f16x8*)&As[ks * 4096 + (wm + i * 16 + l15) * 32 + quad * 8];
#pragma unroll
            for (int i = 0; i < NF; ++i)
                b[i] = *(const f16x8*)&Bs[ks * (BN * 32) + (wn + i * 16 + l15) * 32 + quad * 8];
#pragma unroll
            for (int mi = 0; mi < 4; ++mi)
#pragma unroll
                for (int ni = 0; ni < NF; ++ni)
                    acc[mi][ni] = MFMA_F16(a[mi], b[ni], acc[mi][ni]);
        }
    }

#pragma unroll
    for (int mi = 0; mi < 4; ++mi) {
#pragma unroll
        for (int r = 0; r < 4; ++r) {
            int row = m0 + wm + mi * 16 + quad * 4 + r;
            int b_ = row >> 11, tok = row & 2047;
#pragma unroll
            for (int ni = 0; ni < NF; ++ni) {
                int col = n0 + wn + ni * 16 + l15;
                float v = acc[mi][ni][r] + bias[col];
                size_t addr;
                if (MODE == 0) {
                    addr = (size_t)row * 1024 + col;
                } else if (MODE == 1) {
                    v *= QSCALE;
                    int bh = b_ * 16 + (col >> 6);
                    addr = ((size_t)bh * 2048 + tok) * 64 + (col & 63);
                } else if (MODE == 2) {
                    int tg = roff + tok;
                    int bh = b_ * 16 + (col >> 6);
                    addr = (size_t)bh * 262144 + (size_t)(tg >> 7) * 8192
                         + (size_t)((col >> 5) & 1) * 4096 + (tg & 127) * 32 + (col & 31);
                } else {
                    int tg = roff + tok;
                    int bh = b_ * 16 + (col >> 6);
                    addr = (size_t)bh * 262144 + (size_t)tg * 64 + (col & 63);
                }
                out[addr] = (OutT)v;
            }
        }
    }
}

// ---------------------------------------------------------------------------
// V transpose: vbuf [bh][4096][64] -> vt tiles [bh][kt][kks][d64][32kk]
// ---------------------------------------------------------------------------
__global__ __launch_bounds__(256) void transpose_v(
    const f16* __restrict__ vbuf, f16* __restrict__ vt)
{
    const int t = threadIdx.x;
    const int mt = t >> 3, md = t & 7;          // token-group, d-group
    const int tok0 = blockIdx.x * 256 + mt * 8;
    const int z = blockIdx.y;                   // bh
    f16x8 in[8];
#pragma unroll
    for (int i = 0; i < 8; ++i)
        in[i] = *(const f16x8*)&vbuf[((size_t)z * 4096 + tok0 + i) * 64 + md * 8];
    f16x8 ov[8];
#pragma unroll
    for (int j = 0; j < 8; ++j)
#pragma unroll
        for (int i = 0; i < 8; ++i) ov[j][i] = in[i][j];
    const int kt = tok0 >> 7, kks = (tok0 >> 5) & 3, kko = tok0 & 31;
#pragma unroll
    for (int j = 0; j < 8; ++j)
        *(f16x8*)&vt[(size_t)z * 262144 + (size_t)kt * 8192 + kks * 2048
                     + (md * 8 + j) * 32 + kko] = ov[j];
}

// ---------------------------------------------------------------------------
// Flash attention, S^T form, TK=128 keys/iter (32 iters).
// Grid (bh=32, qt=32): bh on x -> 4 heads per XCD -> K/V L2-resident.
// 256 thr = 4 waves; wave owns 16 q-rows. 36 MFMA per 2 barriers.
// P roundtrip uses wave-private LDS (no block barrier needed).
// ---------------------------------------------------------------------------
__global__ __launch_bounds__(256) void attn_kernel(
    const f16* __restrict__ q, const f16* __restrict__ kb,
    const f16* __restrict__ vtb, f16* __restrict__ o)
{
    __shared__ alignas(16) f16 K_lds[8192];        // [ks2][tok128][32]
    __shared__ alignas(16) f16 V_lds[8192];        // [kks4][d64][32]
    __shared__ alignas(16) f16 P_lds[4][16][136];  // per-wave [q16][kk128 +8]

    const int tid = threadIdx.x;
    const int w = tid >> 6, lane = tid & 63, quad = lane >> 4, l15 = lane & 15;
    const int bh = blockIdx.x, qt = blockIdx.y;
    const int b = bh >> 4, h = bh & 15;
    const int qbase = qt * 64;

    // Q as B-frag: B[n=qrow(l15)][k=d(quad*8+j)], pre-scaled by QSCALE
    const size_t qaddr = ((size_t)bh * 2048 + qbase + w * 16 + l15) * 64 + quad * 8;
    const f16x8 qa0 = *(const f16x8*)&q[qaddr];
    const f16x8 qa1 = *(const f16x8*)&q[qaddr + 32];

    f16x8 ones;
#pragma unroll
    for (int j = 0; j < 8; ++j) ones[j] = (f16)1.0f;

    f32x4 o_acc[4] = {};
    f32x4 l_acc = {};

    const f16* ktile = kb + (size_t)bh * 262144;
    const f16* vtile = vtb + (size_t)bh * 262144;
    const int coff = tid * 8;            // identity chunk mapping
    f16* kl = &K_lds[w * 512];
    f16* vl = &V_lds[w * 512];

    for (int kt = 0; kt < 32; ++kt) {
        __syncthreads();
#pragma unroll
        for (int p = 0; p < 4; ++p) {
            glds16(&ktile[coff + p * 2048], kl + p * 2048);
            glds16(&vtile[coff + p * 2048], vl + p * 2048);
        }
        ktile += 8192; vtile += 8192;
        __syncthreads();

        // S^T: D[m=kk][n=qrow]; A = K rows (natural), B = Q frags
        f32x4 s[8];
#pragma unroll
        for (int mt = 0; mt < 8; ++mt) {
            f16x8 ka0 = *(const f16x8*)&K_lds[(mt * 16 + l15) * 32 + quad * 8];
            f16x8 ka1 = *(const f16x8*)&K_lds[4096 + (mt * 16 + l15) * 32 + quad * 8];
            f32x4 t = {};
            t = MFMA_F16(ka0, qa0, t);
            t = MFMA_F16(ka1, qa1, t);
            s[mt] = t;
        }

        // P = exp2(s - EXPOFF), packed writes into wave-private P
#pragma unroll
        for (int mt = 0; mt < 8; ++mt) {
            f16x4v pk;
#pragma unroll
            for (int r = 0; r < 4; ++r)
                pk[r] = (f16)__builtin_amdgcn_exp2f(s[mt][r] - EXPOFF);
            *(f16x4v*)&P_lds[w][l15][mt * 16 + quad * 4] = pk;
        }

        // same-wave LDS ops are in-order: read back P as A-frags
        f16x8 pa[4];
#pragma unroll
        for (int ks = 0; ks < 4; ++ks)
            pa[ks] = *(const f16x8*)&P_lds[w][l15][ks * 32 + quad * 8];

#pragma unroll
        for (int ks = 0; ks < 4; ++ks)
            l_acc = MFMA_F16(ones, pa[ks], l_acc);

#pragma unroll
        for (int dt = 0; dt < 4; ++dt) {
#pragma unroll
            for (int ks = 0; ks < 4; ++ks) {
                f16x8 vb = *(const f16x8*)&V_lds[ks * 2048 + (dt * 16 + l15) * 32 + quad * 8];
                o_acc[dt] = MFMA_F16(pa[ks], vb, o_acc[dt]);
            }
        }
    }

    // epilogue: o_acc[dt][r] = O[q=quad*4+r][d=dt*16+l15]; l at lane l15=q
#pragma unroll
    for (int r = 0; r < 4; ++r) {
        float lr = __shfl(l_acc[0], quad * 4 + r, 64);
        float inv = 1.0f / lr;
        int row_local = w * 16 + quad * 4 + r;
        size_t obase = ((size_t)(b * 2048 + qbase + row_local)) * 1024 + h * 64;
#pragma unroll
        for (int dt = 0; dt < 4; ++dt)
            o[obase + dt * 16 + l15] = (f16)(o_acc[dt][r] * inv);
    }
}

// ---------------------------------------------------------------------------
// Host launcher
// ---------------------------------------------------------------------------
extern "C" void kernel_launch(void* const* d_in, const int* in_sizes, int n_in,
                              void* d_out, int out_size, void* d_ws, size_t ws_size,
                              hipStream_t stream)
{
    (void)in_sizes; (void)n_in; (void)out_size; (void)ws_size;

    const float* x    = (const float*)d_in[0];
    const float* ctx  = (const float*)d_in[1];
    const float* Wq   = (const float*)d_in[2];  const float* bq  = (const float*)d_in[3];
    const float* Wks  = (const float*)d_in[4];  const float* bks = (const float*)d_in[5];
    const float* Wvs  = (const float*)d_in[6];  const float* bvs = (const float*)d_in[7];
    const float* Wkc  = (const float*)d_in[8];  const float* bkc = (const float*)d_in[9];
    const float* Wvc  = (const float*)d_in[10]; const float* bvc = (const float*)d_in[11];
    const float* Wo   = (const float*)d_in[12]; const float* bo  = (const float*)d_in[13];

    char* ws = (char*)d_ws;
    f16* xb   = (f16*)(ws + 0);          //  8 MB (dead after proj)
    f16* cb   = (f16*)(ws + 8388608);    //  8 MB (dead after proj)
    f16* vt   = (f16*)(ws + 0);          // 16 MB, reuses xb+cb
    f16* wt   = (f16*)(ws + 16777216);   // 12 MB 6 x [1024][1024]
    f16* qbuf = (f16*)(ws + 29360128);   //  8 MB [bh][2048][64]
    f16* kbuf = (f16*)(ws + 37748736);   // 16 MB tiled
    f16* vbuf = (f16*)(ws + 54525952);   // 16 MB [bh][4096][64]
    f16* abuf = (f16*)(ws + 71303168);   //  8 MB (end 79,691,776)

    convert_xc<<<8192, 256, 0, stream>>>((const float4*)x, (const float4*)ctx,
                                         (f16x4v*)xb, (f16x4v*)cb);
    pack_w<<<dim3(32, 32, 6), 256, 0, stream>>>(Wq, Wks, Wvs, Wkc, Wvc, Wo, wt);

    gemm_kernel<1, 128, f16><<<dim3(32, 8, 1), 256, 0, stream>>>(
        xb, xb, wt, bq, bq, qbuf);
    gemm_kernel<2, 128, f16><<<dim3(32, 8, 2), 256, 0, stream>>>(
        xb, cb, wt + 1 * 1048576, bks, bkc, kbuf);
    gemm_kernel<3, 128, f16><<<dim3(32, 8, 2), 256, 0, stream>>>(
        xb, cb, wt + 2 * 1048576, bvs, bvc, vbuf);

    transpose_v<<<dim3(16, 32), 256, 0, stream>>>(vbuf, vt);
    attn_kernel<<<dim3(32, 32), 256, 0, stream>>>(qbuf, kbuf, vt, abuf);

    gemm_kernel<0, 64, float><<<dim3(32, 16, 1), 256, 0, stream>>>(
        abuf, abuf, wt + 5 * 1048576, bo, bo, (float*)d_out);
}

// Round 4
// 322.414 us; speedup vs baseline: 1.1032x; 1.1032x over previous
//
#include <hip/hip_runtime.h>
#include <hip/hip_bf16.h>
#include <math.h>

// ---------------------------------------------------------------------------
// JointAttention fp16 MFMA pipeline.
//   convert fp32->fp16 -> pack W^T -> Q/K/V proj GEMMs (BK=32 m97-shape, glds,
//   head-blocked tile-contiguous outputs) -> V transpose -> flash attn
//   (S^T form, TK=64, 32 q-rows/wave, exp2 no-max softmax, VALU l-reduce,
//   2 barriers/iter) -> output GEMM (128x64 tiles, fp32 out).
// Layouts:
//   qbuf [bh][2048][64]                 (Q pre-scaled by 0.125*log2e)
//   kbuf [bh][kt64][ks2][tok64][32]     (8KB contiguous staging tiles)
//   vbuf [bh][4096][64]
//   vt   [bh][kt64][kks2][d64][32]      (8KB contiguous V^T staging tiles)
//   abuf [tok4096][1024]
// ---------------------------------------------------------------------------

typedef _Float16 f16;
typedef _Float16 f16x8 __attribute__((ext_vector_type(8)));
typedef _Float16 f16x4v __attribute__((ext_vector_type(4)));
typedef float    f32x4 __attribute__((ext_vector_type(4)));

#define MFMA_F16(a, b, c) __builtin_amdgcn_mfma_f32_16x16x32_f16((a), (b), (c), 0, 0, 0)

#define QSCALE 0.18033688011112042f   // 0.125 * log2(e)
#define EXPOFF 7.2134752044448170f    // 5 * log2(e)

__device__ __forceinline__ void glds16(const f16* g, f16* l) {
    __builtin_amdgcn_global_load_lds(
        (const __attribute__((address_space(1))) void*)g,
        (__attribute__((address_space(3))) void*)l, 16, 0, 0);
}

// ---------------------------------------------------------------------------
// fp32 -> fp16 convert of x and context
// ---------------------------------------------------------------------------
__global__ __launch_bounds__(256) void convert_xc(
    const float4* __restrict__ x, const float4* __restrict__ ctx,
    f16x4v* __restrict__ xb, f16x4v* __restrict__ cb)
{
    const int n4 = (2 * 2048 * 1024) / 4;
    int i = blockIdx.x * 256 + threadIdx.x;
    float4 v;
    f16x4v* dst;
    if (i < n4) { v = x[i];        dst = xb + i; }
    else        { v = ctx[i - n4]; dst = cb + (i - n4); }
    f16x4v h = { (f16)v.x, (f16)v.y, (f16)v.z, (f16)v.w };
    *dst = h;
}

// ---------------------------------------------------------------------------
// pack 6 weights W[K][N] fp32 -> Wt[N][K] fp16
// ---------------------------------------------------------------------------
__global__ __launch_bounds__(256) void pack_w(
    const float* __restrict__ W0, const float* __restrict__ W1,
    const float* __restrict__ W2, const float* __restrict__ W3,
    const float* __restrict__ W4, const float* __restrict__ W5,
    f16* __restrict__ out)
{
    const float* Ws[6] = { W0, W1, W2, W3, W4, W5 };
    const float* W = Ws[blockIdx.z];
    f16* Wt = out + (size_t)blockIdx.z * (1024 * 1024);

    __shared__ float tile[32][33];
    const int tx = threadIdx.x & 31, ty = threadIdx.x >> 5;
    const int n0 = blockIdx.x * 32, k0 = blockIdx.y * 32;

#pragma unroll
    for (int i = 0; i < 4; ++i) {
        int r = i * 8 + ty;
        tile[r][tx] = W[(size_t)(k0 + r) * 1024 + n0 + tx];
    }
    __syncthreads();
#pragma unroll
    for (int i = 0; i < 4; ++i) {
        int r = i * 8 + ty;
        Wt[(size_t)(n0 + r) * 1024 + k0 + tx] = (f16)tile[tx][r];
    }
}

// ---------------------------------------------------------------------------
// GEMM 128xBN tile, BK=32 (m97 shape: 16 KB LDS, high occupancy), glds.
// MODE: 0 = fp32 out [row][1024]
//       1 = Q: scale by QSCALE, head-blocked [bh][2048][64]
//       2 = K: tiled [bh][kt64][ks2][tok64][32]
//       3 = V: head-blocked [bh][4096][64]
// ---------------------------------------------------------------------------
template <int MODE, int BN, typename OutT>
__global__ __launch_bounds__(256) void gemm_kernel(
    const f16* __restrict__ A0, const f16* __restrict__ A1,
    const f16* __restrict__ Wt,
    const float* __restrict__ bias0, const float* __restrict__ bias1,
    OutT* __restrict__ out)
{
    __shared__ alignas(16) f16 As[128 * 32];      // 8 KB
    __shared__ alignas(16) f16 Bs[BN * 32];       // 8/4 KB

    const int z = blockIdx.z;
    const f16* A = z ? A1 : A0;
    const f16* Bt = Wt + (size_t)z * 2097152;
    const float* bias = z ? bias1 : bias0;
    const int roff = z * 2048;

    const int m0 = blockIdx.x * 128, n0 = blockIdx.y * BN;
    const int tid = threadIdx.x;
    const int w = tid >> 6, lane = tid & 63, quad = lane >> 4, l15 = lane & 15;
    const int wm = (w >> 1) * 64, wn = (w & 1) * (BN / 2);
    constexpr int NF = BN / 32;
    constexpr int BPASS = BN / 64;     // 16B chunks: BN*4/256

    int gA[2], gB[BPASS];
#pragma unroll
    for (int p = 0; p < 2; ++p) {
        int c = tid + p * 256;
        gA[p] = (m0 + ((c >> 2) & 127)) * 1024 + (c & 3) * 8;
    }
#pragma unroll
    for (int p = 0; p < BPASS; ++p) {
        int c = tid + p * 256;
        gB[p] = (n0 + ((c >> 2) & (BN - 1))) * 1024 + (c & 3) * 8;
    }

    f32x4 acc[4][NF] = {};

    for (int k0 = 0; k0 < 1024; k0 += 32) {
        __syncthreads();
#pragma unroll
        for (int p = 0; p < 2; ++p)
            glds16(&A[gA[p] + k0], &As[(p * 256 + w * 64) * 8]);
#pragma unroll
        for (int p = 0; p < BPASS; ++p)
            glds16(&Bt[gB[p] + k0], &Bs[(p * 256 + w * 64) * 8]);
        __syncthreads();

        f16x8 a[4], b[NF];
#pragma unroll
        for (int i = 0; i < 4; ++i)
            a[i] = *(const f16x8*)&As[(wm + i * 16 + l15) * 32 + quad * 8];
#pragma unroll
        for (int i = 0; i < NF; ++i)
            b[i] = *(const f16x8*)&Bs[(wn + i * 16 + l15) * 32 + quad * 8];
#pragma unroll
        for (int mi = 0; mi < 4; ++mi)
#pragma unroll
            for (int ni = 0; ni < NF; ++ni)
                acc[mi][ni] = MFMA_F16(a[mi], b[ni], acc[mi][ni]);
    }

#pragma unroll
    for (int mi = 0; mi < 4; ++mi) {
#pragma unroll
        for (int r = 0; r < 4; ++r) {
            int row = m0 + wm + mi * 16 + quad * 4 + r;
            int b_ = row >> 11, tok = row & 2047;
#pragma unroll
            for (int ni = 0; ni < NF; ++ni) {
                int col = n0 + wn + ni * 16 + l15;
                float v = acc[mi][ni][r] + bias[col];
                size_t addr;
                if (MODE == 0) {
                    addr = (size_t)row * 1024 + col;
                } else if (MODE == 1) {
                    v *= QSCALE;
                    int bh = b_ * 16 + (col >> 6);
                    addr = ((size_t)bh * 2048 + tok) * 64 + (col & 63);
                } else if (MODE == 2) {
                    int tg = roff + tok;
                    int bh = b_ * 16 + (col >> 6);
                    addr = (size_t)bh * 262144 + (size_t)(tg >> 6) * 4096
                         + (size_t)((col >> 5) & 1) * 2048 + (tg & 63) * 32 + (col & 31);
                } else {
                    int tg = roff + tok;
                    int bh = b_ * 16 + (col >> 6);
                    addr = (size_t)bh * 262144 + (size_t)tg * 64 + (col & 63);
                }
                out[addr] = (OutT)v;
            }
        }
    }
}

// ---------------------------------------------------------------------------
// V transpose: vbuf [bh][4096][64] -> vt tiles [bh][kt64][kks2][d64][32kk]
// ---------------------------------------------------------------------------
__global__ __launch_bounds__(256) void transpose_v(
    const f16* __restrict__ vbuf, f16* __restrict__ vt)
{
    const int t = threadIdx.x;
    const int mt = t >> 3, md = t & 7;
    const int tok0 = blockIdx.x * 256 + mt * 8;
    const int z = blockIdx.y;                   // bh
    f16x8 in[8];
#pragma unroll
    for (int i = 0; i < 8; ++i)
        in[i] = *(const f16x8*)&vbuf[((size_t)z * 4096 + tok0 + i) * 64 + md * 8];
    f16x8 ov[8];
#pragma unroll
    for (int j = 0; j < 8; ++j)
#pragma unroll
        for (int i = 0; i < 8; ++i) ov[j][i] = in[i][j];
    const int kt = tok0 >> 6, kks = (tok0 >> 5) & 1, kko = tok0 & 31;
#pragma unroll
    for (int j = 0; j < 8; ++j)
        *(f16x8*)&vt[(size_t)z * 262144 + (size_t)kt * 4096 + kks * 2048
                     + (md * 8 + j) * 32 + kko] = ov[j];
}

// ---------------------------------------------------------------------------
// Flash attention, S^T form, TK=64 keys/iter (64 iters).
// Grid (bh=32, qt=16) = 512 blocks = 2/CU, 8 waves/CU. 256 thr = 4 waves;
// wave owns 32 q-rows (nq=2 frag groups) -> 32 MFMA per 20 b128 reads per
// iter, 2 barriers. l summed on VALU from S^T C-layout (each lane holds 16
// scores of ONE q-row) + 2 shfl_xor. LDS 34.8 KB.
// ---------------------------------------------------------------------------
__global__ __launch_bounds__(256, 2) void attn_kernel(
    const f16* __restrict__ q, const f16* __restrict__ kb,
    const f16* __restrict__ vtb, f16* __restrict__ o)
{
    __shared__ alignas(16) f16 K_lds[4096];      // [ks2][tok64][32]
    __shared__ alignas(16) f16 V_lds[4096];      // [kks2][d64][32]
    __shared__ alignas(16) f16 P_lds[128 * 72];  // [w*32+qlocal][kk64 +8 pad]

    const int tid = threadIdx.x;
    const int w = tid >> 6, lane = tid & 63, quad = lane >> 4, l15 = lane & 15;
    const int bh = blockIdx.x, qt = blockIdx.y;
    const int b = bh >> 4, h = bh & 15;
    const int qbase = qt * 128;

    // Q as B-frag: B[n=qrow(l15)][k=d(quad*8+j)], pre-scaled by QSCALE
    f16x8 qa[2][2];
#pragma unroll
    for (int nq = 0; nq < 2; ++nq) {
        const size_t qaddr =
            ((size_t)bh * 2048 + qbase + w * 32 + nq * 16 + l15) * 64 + quad * 8;
        qa[nq][0] = *(const f16x8*)&q[qaddr];
        qa[nq][1] = *(const f16x8*)&q[qaddr + 32];
    }

    f32x4 o_acc[2][4] = {};
    float l_acc[2] = { 0.f, 0.f };

    const f16* ktile = kb + (size_t)bh * 262144;
    const f16* vtile = vtb + (size_t)bh * 262144;
    const int coff = tid * 8;                    // identity chunk mapping
    f16* kl0 = &K_lds[w * 512];
    f16* kl1 = &K_lds[2048 + w * 512];
    f16* vl0 = &V_lds[w * 512];
    f16* vl1 = &V_lds[2048 + w * 512];

    for (int kt = 0; kt < 64; ++kt) {
        __syncthreads();
        glds16(ktile + coff, kl0);
        glds16(ktile + 2048 + coff, kl1);
        glds16(vtile + coff, vl0);
        glds16(vtile + 2048 + coff, vl1);
        ktile += 4096; vtile += 4096;
        __syncthreads();

        // S^T = K Q^T: D[m=kk][n=qrow]; A = K rows (natural layout)
        f32x4 s[4][2];
#pragma unroll
        for (int mt = 0; mt < 4; ++mt) {
            f16x8 ka0 = *(const f16x8*)&K_lds[(mt * 16 + l15) * 32 + quad * 8];
            f16x8 ka1 = *(const f16x8*)&K_lds[2048 + (mt * 16 + l15) * 32 + quad * 8];
#pragma unroll
            for (int nq = 0; nq < 2; ++nq) {
                f32x4 t = {};
                t = MFMA_F16(ka0, qa[nq][0], t);
                t = MFMA_F16(ka1, qa[nq][1], t);
                s[mt][nq] = t;
            }
        }

        // P = exp2(s - EXPOFF); per-lane l partial (16 scores of q=nq*16+l15)
        float lp[2] = { 0.f, 0.f };
#pragma unroll
        for (int mt = 0; mt < 4; ++mt) {
#pragma unroll
            for (int nq = 0; nq < 2; ++nq) {
                f16x4v pk;
#pragma unroll
                for (int r = 0; r < 4; ++r) {
                    float e = __builtin_amdgcn_exp2f(s[mt][nq][r] - EXPOFF);
                    lp[nq] += e;
                    pk[r] = (f16)e;
                }
                *(f16x4v*)&P_lds[(w * 32 + nq * 16 + l15) * 72 + mt * 16 + quad * 4] = pk;
            }
        }
#pragma unroll
        for (int nq = 0; nq < 2; ++nq) {
            lp[nq] += __shfl_xor(lp[nq], 16, 64);   // reduce over quads
            lp[nq] += __shfl_xor(lp[nq], 32, 64);
            l_acc[nq] += lp[nq];
        }

        // P as A-frag (wave-private LDS, same-wave ordering; no barrier)
        f16x8 pa[2][2];
#pragma unroll
        for (int nq = 0; nq < 2; ++nq)
#pragma unroll
            for (int ks = 0; ks < 2; ++ks)
                pa[nq][ks] = *(const f16x8*)&P_lds[(w * 32 + nq * 16 + l15) * 72 + ks * 32 + quad * 8];

#pragma unroll
        for (int dt = 0; dt < 4; ++dt) {
            f16x8 vb0 = *(const f16x8*)&V_lds[(dt * 16 + l15) * 32 + quad * 8];
            f16x8 vb1 = *(const f16x8*)&V_lds[2048 + (dt * 16 + l15) * 32 + quad * 8];
#pragma unroll
            for (int nq = 0; nq < 2; ++nq) {
                o_acc[nq][dt] = MFMA_F16(pa[nq][0], vb0, o_acc[nq][dt]);
                o_acc[nq][dt] = MFMA_F16(pa[nq][1], vb1, o_acc[nq][dt]);
            }
        }
    }

    // epilogue: o_acc[nq][dt][r] = O[q=nq*16+quad*4+r][d=dt*16+l15]
#pragma unroll
    for (int nq = 0; nq < 2; ++nq) {
#pragma unroll
        for (int r = 0; r < 4; ++r) {
            float lr = __shfl(l_acc[nq], quad * 4 + r, 64);
            float inv = 1.0f / lr;
            int ql = w * 32 + nq * 16 + quad * 4 + r;
            size_t obase = ((size_t)(b * 2048 + qbase + ql)) * 1024 + h * 64;
#pragma unroll
            for (int dt = 0; dt < 4; ++dt)
                o[obase + dt * 16 + l15] = (f16)(o_acc[nq][dt][r] * inv);
        }
    }
}

// ---------------------------------------------------------------------------
// Host launcher
// ---------------------------------------------------------------------------
extern "C" void kernel_launch(void* const* d_in, const int* in_sizes, int n_in,
                              void* d_out, int out_size, void* d_ws, size_t ws_size,
                              hipStream_t stream)
{
    (void)in_sizes; (void)n_in; (void)out_size; (void)ws_size;

    const float* x    = (const float*)d_in[0];
    const float* ctx  = (const float*)d_in[1];
    const float* Wq   = (const float*)d_in[2];  const float* bq  = (const float*)d_in[3];
    const float* Wks  = (const float*)d_in[4];  const float* bks = (const float*)d_in[5];
    const float* Wvs  = (const float*)d_in[6];  const float* bvs = (const float*)d_in[7];
    const float* Wkc  = (const float*)d_in[8];  const float* bkc = (const float*)d_in[9];
    const float* Wvc  = (const float*)d_in[10]; const float* bvc = (const float*)d_in[11];
    const float* Wo   = (const float*)d_in[12]; const float* bo  = (const float*)d_in[13];

    char* ws = (char*)d_ws;
    f16* xb   = (f16*)(ws + 0);          //  8 MB (dead after proj)
    f16* cb   = (f16*)(ws + 8388608);    //  8 MB (dead after proj)
    f16* vt   = (f16*)(ws + 0);          // 16 MB, reuses xb+cb
    f16* wt   = (f16*)(ws + 16777216);   // 12 MB 6 x [1024][1024]
    f16* qbuf = (f16*)(ws + 29360128);   //  8 MB [bh][2048][64]
    f16* kbuf = (f16*)(ws + 37748736);   // 16 MB tiled
    f16* vbuf = (f16*)(ws + 54525952);   // 16 MB [bh][4096][64]
    f16* abuf = (f16*)(ws + 71303168);   //  8 MB (end 79,691,776)

    convert_xc<<<8192, 256, 0, stream>>>((const float4*)x, (const float4*)ctx,
                                         (f16x4v*)xb, (f16x4v*)cb);
    pack_w<<<dim3(32, 32, 6), 256, 0, stream>>>(Wq, Wks, Wvs, Wkc, Wvc, Wo, wt);

    gemm_kernel<1, 128, f16><<<dim3(32, 8, 1), 256, 0, stream>>>(
        xb, xb, wt, bq, bq, qbuf);
    gemm_kernel<2, 128, f16><<<dim3(32, 8, 2), 256, 0, stream>>>(
        xb, cb, wt + 1 * 1048576, bks, bkc, kbuf);
    gemm_kernel<3, 128, f16><<<dim3(32, 8, 2), 256, 0, stream>>>(
        xb, cb, wt + 2 * 1048576, bvs, bvc, vbuf);

    transpose_v<<<dim3(16, 32), 256, 0, stream>>>(vbuf, vt);
    attn_kernel<<<dim3(32, 16), 256, 0, stream>>>(qbuf, kbuf, vt, abuf);

    gemm_kernel<0, 64, float><<<dim3(32, 16, 1), 256, 0, stream>>>(
        abuf, abuf, wt + 5 * 1048576, bo, bo, (float*)d_out);
}

// Round 5
// 317.804 us; speedup vs baseline: 1.1192x; 1.0145x over previous
//
#include <hip/hip_runtime.h>
#include <hip/hip_bf16.h>
#include <math.h>

// ---------------------------------------------------------------------------
// JointAttention fp16 MFMA pipeline.  See per-kernel comments.
// Swizzle: LDS chunk col c' = c ^ ((row>>1)&3) baked into glds global addr;
//   readers use qsw = (quad ^ ((l15>>1)&3))*8 -> 2-way-only bank aliasing.
// ---------------------------------------------------------------------------

typedef _Float16 f16;
typedef _Float16 f16x8 __attribute__((ext_vector_type(8)));
typedef _Float16 f16x4v __attribute__((ext_vector_type(4)));
typedef float    f32x4 __attribute__((ext_vector_type(4)));

#define MFMA_F16(a, b, c) __builtin_amdgcn_mfma_f32_16x16x32_f16((a), (b), (c), 0, 0, 0)

#define QSCALE 0.18033688011112042f   // 0.125 * log2(e)

__device__ __forceinline__ void glds16(const f16* g, f16* l) {
    __builtin_amdgcn_global_load_lds(
        (const __attribute__((address_space(1))) void*)g,
        (__attribute__((address_space(3))) void*)l, 16, 0, 0);
}

__global__ __launch_bounds__(256) void convert_xc(
    const float4* __restrict__ x, const float4* __restrict__ ctx,
    f16x4v* __restrict__ xb, f16x4v* __restrict__ cb)
{
    const int n4 = (2 * 2048 * 1024) / 4;
    int i = blockIdx.x * 256 + threadIdx.x;
    float4 v;
    f16x4v* dst;
    if (i < n4) { v = x[i];        dst = xb + i; }
    else        { v = ctx[i - n4]; dst = cb + (i - n4); }
    f16x4v h = { (f16)v.x, (f16)v.y, (f16)v.z, (f16)v.w };
    *dst = h;
}

__global__ __launch_bounds__(256) void pack_w(
    const float* __restrict__ W0, const float* __restrict__ W1,
    const float* __restrict__ W2, const float* __restrict__ W3,
    const float* __restrict__ W4, const float* __restrict__ W5,
    f16* __restrict__ out)
{
    const float* Ws[6] = { W0, W1, W2, W3, W4, W5 };
    const float* W = Ws[blockIdx.z];
    f16* Wt = out + (size_t)blockIdx.z * (1024 * 1024);

    __shared__ float tile[32][33];
    const int tx = threadIdx.x & 31, ty = threadIdx.x >> 5;
    const int n0 = blockIdx.x * 32, k0 = blockIdx.y * 32;

#pragma unroll
    for (int i = 0; i < 4; ++i) {
        int r = i * 8 + ty;
        tile[r][tx] = W[(size_t)(k0 + r) * 1024 + n0 + tx];
    }
    __syncthreads();
#pragma unroll
    for (int i = 0; i < 4; ++i) {
        int r = i * 8 + ty;
        Wt[(size_t)(n0 + r) * 1024 + k0 + tx] = (f16)tile[tx][r];
    }
}

// Shared GEMM staging (128-row A tile, BN-row B tile, BK=32, swizzled glds)
#define GEMM_PROLOGUE(BN)                                                     \
    const int m0 = blockIdx.x * 128, n0 = blockIdx.y * (BN);                  \
    const int tid = threadIdx.x;                                              \
    const int w = tid >> 6, lane = tid & 63, quad = lane >> 4, l15 = lane & 15;\
    const int wm = (w >> 1) * 64, wn = (w & 1) * ((BN) / 2);                  \
    const int qsw = (quad ^ ((l15 >> 1) & 3)) * 8;                            \
    int gA[2], gB[(BN) / 64];                                                 \
    _Pragma("unroll")                                                         \
    for (int p = 0; p < 2; ++p) {                                             \
        int s = tid + p * 256;                                                \
        int r = (s >> 2) & 127, c = (s & 3) ^ ((s >> 3) & 3);                 \
        gA[p] = (m0 + r) * 1024 + c * 8;                                      \
    }                                                                         \
    _Pragma("unroll")                                                         \
    for (int p = 0; p < (BN) / 64; ++p) {                                     \
        int s = tid + p * 256;                                                \
        int r = (s >> 2) & ((BN) - 1), c = (s & 3) ^ ((s >> 3) & 3);          \
        gB[p] = (n0 + r) * 1024 + c * 8;                                      \
    }

#define GEMM_STAGE(BN)                                                        \
    __syncthreads();                                                          \
    _Pragma("unroll")                                                         \
    for (int p = 0; p < 2; ++p) glds16(&A[gA[p] + k0], &As[(p * 256 + w * 64) * 8]); \
    _Pragma("unroll")                                                         \
    for (int p = 0; p < (BN) / 64; ++p) glds16(&Bt[gB[p] + k0], &Bs[(p * 256 + w * 64) * 8]); \
    __syncthreads();

// QK projection GEMM. z: 0=Q, 1=K_self, 2=K_ctx.
__global__ __launch_bounds__(256) void qk_gemm(
    const f16* __restrict__ xb, const f16* __restrict__ cb,
    const f16* __restrict__ wt,
    const float* __restrict__ bq, const float* __restrict__ bks,
    const float* __restrict__ bkc,
    f16* __restrict__ qbuf, f16* __restrict__ kbuf)
{
    __shared__ alignas(16) f16 As[128 * 32];
    __shared__ alignas(16) f16 Bs[128 * 32];

    const int z = blockIdx.z;
    const f16* A = (z == 2) ? cb : xb;
    const f16* Bt = wt + (size_t)(z == 0 ? 0 : (z == 1 ? 1 : 3)) * 1048576;
    const float* bias = (z == 0) ? bq : (z == 1) ? bks : bkc;
    const int roff = (z == 2) ? 2048 : 0;

    GEMM_PROLOGUE(128)
    f32x4 acc[4][4] = {};

    for (int k0 = 0; k0 < 1024; k0 += 32) {
        GEMM_STAGE(128)
        f16x8 a[4], b[4];
#pragma unroll
        for (int i = 0; i < 4; ++i)
            a[i] = *(const f16x8*)&As[(wm + i * 16 + l15) * 32 + qsw];
#pragma unroll
        for (int i = 0; i < 4; ++i)
            b[i] = *(const f16x8*)&Bs[(wn + i * 16 + l15) * 32 + qsw];
#pragma unroll
        for (int mi = 0; mi < 4; ++mi)
#pragma unroll
            for (int ni = 0; ni < 4; ++ni)
                acc[mi][ni] = MFMA_F16(a[mi], b[ni], acc[mi][ni]);
    }

#pragma unroll
    for (int mi = 0; mi < 4; ++mi) {
#pragma unroll
        for (int r = 0; r < 4; ++r) {
            int row = m0 + wm + mi * 16 + quad * 4 + r;
            int b_ = row >> 11, tok = row & 2047;
#pragma unroll
            for (int ni = 0; ni < 4; ++ni) {
                int col = n0 + wn + ni * 16 + l15;
                float v = acc[mi][ni][r] + bias[col];
                int bh = b_ * 16 + (col >> 6);
                if (z == 0) {
                    qbuf[((size_t)bh * 2048 + tok) * 64 + (col & 63)] = (f16)(v * QSCALE);
                } else {
                    int tg = roff + tok;
                    kbuf[(size_t)bh * 262144 + (size_t)(tg >> 6) * 4096
                         + (size_t)((col >> 5) & 1) * 2048 + (tg & 63) * 32 + (col & 31)] = (f16)v;
                }
            }
        }
    }
}

// V projection, swapped operands: MFMA(b,a) transposes D (A/B frag layouts
// identical) -> D[m=wcol][n=tok]; writes V^T tiles [bh][kt][kks2][d64][32kk].
__global__ __launch_bounds__(256) void v_gemm(
    const f16* __restrict__ xb, const f16* __restrict__ cb,
    const f16* __restrict__ wt,
    const float* __restrict__ bvs, const float* __restrict__ bvc,
    f16* __restrict__ vt)
{
    __shared__ alignas(16) f16 As[128 * 32];
    __shared__ alignas(16) f16 Bs[128 * 32];

    const int z = blockIdx.z;
    const f16* A = z ? cb : xb;
    const f16* Bt = wt + (size_t)(z ? 4 : 2) * 1048576;
    const float* bias = z ? bvc : bvs;
    const int roff = z ? 2048 : 0;

    GEMM_PROLOGUE(128)
    f32x4 acc[4][4] = {};

    for (int k0 = 0; k0 < 1024; k0 += 32) {
        GEMM_STAGE(128)
        f16x8 a[4], b[4];
#pragma unroll
        for (int i = 0; i < 4; ++i)
            a[i] = *(const f16x8*)&As[(wm + i * 16 + l15) * 32 + qsw];
#pragma unroll
        for (int i = 0; i < 4; ++i)
            b[i] = *(const f16x8*)&Bs[(wn + i * 16 + l15) * 32 + qsw];
#pragma unroll
        for (int mi = 0; mi < 4; ++mi)
#pragma unroll
            for (int ni = 0; ni < 4; ++ni)
                acc[mi][ni] = MFMA_F16(b[ni], a[mi], acc[mi][ni]);   // swapped
    }

#pragma unroll
    for (int mi = 0; mi < 4; ++mi) {
        int tok = m0 + wm + mi * 16 + l15;
        int b_ = tok >> 11;
        int tg = roff + (tok & 2047);
        size_t tbase = (size_t)(tg >> 6) * 4096 + (size_t)((tg >> 5) & 1) * 2048 + (tg & 31);
#pragma unroll
        for (int ni = 0; ni < 4; ++ni) {
#pragma unroll
            for (int r = 0; r < 4; ++r) {
                int wcol = n0 + wn + ni * 16 + quad * 4 + r;
                float v = acc[mi][ni][r] + bias[wcol];
                int bh = b_ * 16 + (wcol >> 6);
                vt[(size_t)bh * 262144 + tbase + (size_t)(wcol & 63) * 32] = (f16)v;
            }
        }
    }
}

// Output GEMM, 128x64 tiles, fp32 out.
__global__ __launch_bounds__(256) void out_gemm(
    const f16* __restrict__ abuf, const f16* __restrict__ wt5,
    const float* __restrict__ bo, float* __restrict__ out)
{
    __shared__ alignas(16) f16 As[128 * 32];
    __shared__ alignas(16) f16 Bs[64 * 32];

    const f16* A = abuf;
    const f16* Bt = wt5;

    GEMM_PROLOGUE(64)
    f32x4 acc[4][2] = {};

    for (int k0 = 0; k0 < 1024; k0 += 32) {
        GEMM_STAGE(64)
        f16x8 a[4], b[2];
#pragma unroll
        for (int i = 0; i < 4; ++i)
            a[i] = *(const f16x8*)&As[(wm + i * 16 + l15) * 32 + qsw];
#pragma unroll
        for (int i = 0; i < 2; ++i)
            b[i] = *(const f16x8*)&Bs[(wn + i * 16 + l15) * 32 + qsw];
#pragma unroll
        for (int mi = 0; mi < 4; ++mi)
#pragma unroll
            for (int ni = 0; ni < 2; ++ni)
                acc[mi][ni] = MFMA_F16(a[mi], b[ni], acc[mi][ni]);
    }

#pragma unroll
    for (int mi = 0; mi < 4; ++mi) {
#pragma unroll
        for (int r = 0; r < 4; ++r) {
            int row = m0 + wm + mi * 16 + quad * 4 + r;
#pragma unroll
            for (int ni = 0; ni < 2; ++ni) {
                int col = n0 + wn + ni * 16 + l15;
                out[(size_t)row * 1024 + col] = acc[mi][ni][r] + bo[col];
            }
        }
    }
}

// Flash attention, S^T form, TK=64, double-buffered single-barrier K-loop.
__global__ __launch_bounds__(256, 2) void attn_kernel(
    const f16* __restrict__ q, const f16* __restrict__ kb,
    const f16* __restrict__ vtb, f16* __restrict__ o)
{
    __shared__ alignas(16) f16 K_lds[2][4096];     // [buf][ks2][tok64][32]
    __shared__ alignas(16) f16 V_lds[2][4096];     // [buf][kks2][d64][32]
    __shared__ alignas(16) f16 P_lds[128 * 72];    // [w*32+q][kk64 +8 pad]

    const int tid = threadIdx.x;
    const int w = tid >> 6, lane = tid & 63, quad = lane >> 4, l15 = lane & 15;
    const int bh = blockIdx.x, qt = blockIdx.y;
    const int b = bh >> 4, h = bh & 15;
    const int qbase = qt * 128;

    f16x8 qa[2][2];
#pragma unroll
    for (int nq = 0; nq < 2; ++nq) {
        const size_t qaddr =
            ((size_t)bh * 2048 + qbase + w * 32 + nq * 16 + l15) * 64 + quad * 8;
        qa[nq][0] = *(const f16x8*)&q[qaddr];
        qa[nq][1] = *(const f16x8*)&q[qaddr + 32];
    }

    f16x8 ones;
#pragma unroll
    for (int j = 0; j < 8; ++j) ones[j] = (f16)1.0f;

    f32x4 o_acc[2][4] = {};
    f32x4 l_acc[2] = {};

    const f16* ktile = kb + (size_t)bh * 262144;
    const f16* vtile = vtb + (size_t)bh * 262144;

    const int sco = ((tid >> 2) * 4 + ((tid & 3) ^ ((tid >> 3) & 3))) * 8;
    const int qsw = (quad ^ ((l15 >> 1) & 3)) * 8;
    const int wslot = w * 512;

    glds16(ktile + sco,        &K_lds[0][wslot]);
    glds16(ktile + 2048 + sco, &K_lds[0][2048 + wslot]);
    glds16(vtile + sco,        &V_lds[0][wslot]);
    glds16(vtile + 2048 + sco, &V_lds[0][2048 + wslot]);

    for (int kt = 0; kt < 64; ++kt) {
        const f16* Kc = K_lds[kt & 1];
        const f16* Vc = V_lds[kt & 1];
        f16* Kn = K_lds[(kt + 1) & 1];
        f16* Vn = V_lds[(kt + 1) & 1];

        __syncthreads();   // vmcnt(0) drain: tile kt resident; prev reads done

        // prefetch kt+1 overlaps compute of kt (kt=63 reads adjacent valid ws)
        ktile += 4096; vtile += 4096;
        glds16(ktile + sco,        Kn + wslot);
        glds16(ktile + 2048 + sco, Kn + 2048 + wslot);
        glds16(vtile + sco,        Vn + wslot);
        glds16(vtile + 2048 + sco, Vn + 2048 + wslot);

        f32x4 s[4][2];
#pragma unroll
        for (int mt = 0; mt < 4; ++mt) {
            f16x8 ka0 = *(const f16x8*)&Kc[(mt * 16 + l15) * 32 + qsw];
            f16x8 ka1 = *(const f16x8*)&Kc[2048 + (mt * 16 + l15) * 32 + qsw];
#pragma unroll
            for (int nq = 0; nq < 2; ++nq) {
                f32x4 t = {};
                t = MFMA_F16(ka0, qa[nq][0], t);
                t = MFMA_F16(ka1, qa[nq][1], t);
                s[mt][nq] = t;
            }
        }

#pragma unroll
        for (int mt = 0; mt < 4; ++mt) {
#pragma unroll
            for (int nq = 0; nq < 2; ++nq) {
                f16x4v pk;
#pragma unroll
                for (int r = 0; r < 4; ++r)
                    pk[r] = (f16)__builtin_amdgcn_exp2f(s[mt][nq][r]);
                *(f16x4v*)&P_lds[(w * 32 + nq * 16 + l15) * 72 + mt * 16 + quad * 4] = pk;
            }
        }

        f16x8 pa[2][2];
#pragma unroll
        for (int nq = 0; nq < 2; ++nq)
#pragma unroll
            for (int ks = 0; ks < 2; ++ks)
                pa[nq][ks] = *(const f16x8*)&P_lds[(w * 32 + nq * 16 + l15) * 72 + ks * 32 + quad * 8];

#pragma unroll
        for (int nq = 0; nq < 2; ++nq) {
            l_acc[nq] = MFMA_F16(ones, pa[nq][0], l_acc[nq]);
            l_acc[nq] = MFMA_F16(ones, pa[nq][1], l_acc[nq]);
        }

#pragma unroll
        for (int dt = 0; dt < 4; ++dt) {
            f16x8 vb0 = *(const f16x8*)&Vc[(dt * 16 + l15) * 32 + qsw];
            f16x8 vb1 = *(const f16x8*)&Vc[2048 + (dt * 16 + l15) * 32 + qsw];
#pragma unroll
            for (int nq = 0; nq < 2; ++nq) {
                o_acc[nq][dt] = MFMA_F16(pa[nq][0], vb0, o_acc[nq][dt]);
                o_acc[nq][dt] = MFMA_F16(pa[nq][1], vb1, o_acc[nq][dt]);
            }
        }
    }

#pragma unroll
    for (int nq = 0; nq < 2; ++nq) {
#pragma unroll
        for (int r = 0; r < 4; ++r) {
            float lr = __shfl(l_acc[nq][0], quad * 4 + r, 64);
            float inv = 1.0f / lr;
            int ql = w * 32 + nq * 16 + quad * 4 + r;
            size_t obase = ((size_t)(b * 2048 + qbase + ql)) * 1024 + h * 64;
#pragma unroll
            for (int dt = 0; dt < 4; ++dt)
                o[obase + dt * 16 + l15] = (f16)(o_acc[nq][dt][r] * inv);
        }
    }
}

extern "C" void kernel_launch(void* const* d_in, const int* in_sizes, int n_in,
                              void* d_out, int out_size, void* d_ws, size_t ws_size,
                              hipStream_t stream)
{
    (void)in_sizes; (void)n_in; (void)out_size; (void)ws_size;

    const float* x    = (const float*)d_in[0];
    const float* ctx  = (const float*)d_in[1];
    const float* Wq   = (const float*)d_in[2];  const float* bq  = (const float*)d_in[3];
    const float* Wks  = (const float*)d_in[4];  const float* bks = (const float*)d_in[5];
    const float* Wvs  = (const float*)d_in[6];  const float* bvs = (const float*)d_in[7];
    const float* Wkc  = (const float*)d_in[8];  const float* bkc = (const float*)d_in[9];
    const float* Wvc  = (const float*)d_in[10]; const float* bvc = (const float*)d_in[11];
    const float* Wo   = (const float*)d_in[12]; const float* bo  = (const float*)d_in[13];

    char* ws = (char*)d_ws;
    f16* xb   = (f16*)(ws + 0);          //  8 MB [4096][1024]
    f16* cb   = (f16*)(ws + 8388608);    //  8 MB [4096][1024]
    f16* wt   = (f16*)(ws + 16777216);   // 12 MB 6 x [1024][1024]
    f16* qbuf = (f16*)(ws + 29360128);   //  8 MB [bh][2048][64]
    f16* kbuf = (f16*)(ws + 37748736);   // 16 MB K tiles
    f16* vt   = (f16*)(ws + 54525952);   // 16 MB V^T tiles
    f16* abuf = (f16*)(ws + 71303168);   //  8 MB (end 79,691,776)

    convert_xc<<<8192, 256, 0, stream>>>((const float4*)x, (const float4*)ctx,
                                         (f16x4v*)xb, (f16x4v*)cb);
    pack_w<<<dim3(32, 32, 6), 256, 0, stream>>>(Wq, Wks, Wvs, Wkc, Wvc, Wo, wt);

    qk_gemm<<<dim3(32, 8, 3), 256, 0, stream>>>(xb, cb, wt, bq, bks, bkc, qbuf, kbuf);
    v_gemm<<<dim3(32, 8, 2), 256, 0, stream>>>(xb, cb, wt, bvs, bvc, vt);

    attn_kernel<<<dim3(32, 16), 256, 0, stream>>>(qbuf, kbuf, vt, abuf);

    out_gemm<<<dim3(32, 16), 256, 0, stream>>>(abuf, wt + 5 * 1048576, bo, (float*)d_out);
}